// Round 1
// baseline (8338.014 us; speedup 1.0000x reference)
//
#include <hip/hip_runtime.h>

// Problem constants (fixed by the reference).
static constexpr int NODES  = 5000000;   // N
static constexpr int EDGES  = 80000000;  // E
static constexpr int GRAPHS = 100000;    // NUM_GRAPHS
static constexpr int NPG    = 50;        // NODES_PER_GRAPH

// ---------------------------------------------------------------------------
// Pass 1: in-degree histogram (edges only; self-loop added as +1 later).
// col4: vectorized int4 view of edge_index[1] (targets).
// ---------------------------------------------------------------------------
__global__ void __launch_bounds__(256) k_deg(const int4* __restrict__ col4,
                                             float* __restrict__ deg) {
    int i = blockIdx.x * 256 + threadIdx.x;
    if (i < EDGES / 4) {
        int4 c = col4[i];
        atomicAdd(&deg[c.x], 1.0f);
        atomicAdd(&deg[c.y], 1.0f);
        atomicAdd(&deg[c.z], 1.0f);
        atomicAdd(&deg[c.w], 1.0f);
    }
}

// ---------------------------------------------------------------------------
// Pass 2: per-node source weight s[i] = x[i]*w * rsqrt(deg[i]+1).
// ---------------------------------------------------------------------------
__global__ void __launch_bounds__(256) k_scale(const float4* __restrict__ x4,
                                               const float4* __restrict__ deg4,
                                               const float* __restrict__ conv_w,
                                               float4* __restrict__ s4) {
    int i = blockIdx.x * 256 + threadIdx.x;
    if (i < NODES / 4) {
        float w = conv_w[0];
        float4 x = x4[i];
        float4 d = deg4[i];
        float4 s;
        s.x = x.x * w * rsqrtf(d.x + 1.0f);
        s.y = x.y * w * rsqrtf(d.y + 1.0f);
        s.z = x.z * w * rsqrtf(d.z + 1.0f);
        s.w = x.w * w * rsqrtf(d.w + 1.0f);
        s4[i] = s;
    }
}

// ---------------------------------------------------------------------------
// Pass 3: edge scatter t[col] += s[row].
// ---------------------------------------------------------------------------
__global__ void __launch_bounds__(256) k_scatter(const int4* __restrict__ row4,
                                                 const int4* __restrict__ col4,
                                                 const float* __restrict__ s,
                                                 float* __restrict__ t) {
    int i = blockIdx.x * 256 + threadIdx.x;
    if (i < EDGES / 4) {
        int4 r = row4[i];
        int4 c = col4[i];
        atomicAdd(&t[c.x], s[r.x]);
        atomicAdd(&t[c.y], s[r.y]);
        atomicAdd(&t[c.z], s[r.z]);
        atomicAdd(&t[c.w], s[r.w]);
    }
}

// ---------------------------------------------------------------------------
// Pass 4: epilogue. h[i] = dis[i]*t[i] + xw[i]/deg[i] + conv_b, then the
// per-graph 50->2 FC: out[g][c] = sum_j h[g*50+j]*fc_w[c][j] + fc_b[c].
// One thread per graph (100k threads); fc_w (100 floats) hits L1.
// ---------------------------------------------------------------------------
__global__ void __launch_bounds__(256) k_final(const float* __restrict__ x,
                                               const float* __restrict__ deg,
                                               const float* __restrict__ t,
                                               const float* __restrict__ conv_w,
                                               const float* __restrict__ conv_b,
                                               const float* __restrict__ fc_w,
                                               const float* __restrict__ fc_b,
                                               float* __restrict__ out) {
    int g = blockIdx.x * 256 + threadIdx.x;
    if (g >= GRAPHS) return;
    float w = conv_w[0];
    float b = conv_b[0];
    float acc0 = 0.0f, acc1 = 0.0f;
    int base = g * NPG;
    #pragma unroll 5
    for (int j = 0; j < NPG; ++j) {
        float d   = deg[base + j] + 1.0f;     // includes self-loop
        float dis = rsqrtf(d);
        float xw  = x[base + j] * w;
        float h   = dis * t[base + j] + xw / d + b;
        acc0 += h * fc_w[j];
        acc1 += h * fc_w[NPG + j];
    }
    out[g * 2 + 0] = acc0 + fc_b[0];
    out[g * 2 + 1] = acc1 + fc_b[1];
}

extern "C" void kernel_launch(void* const* d_in, const int* in_sizes, int n_in,
                              void* d_out, int out_size, void* d_ws, size_t ws_size,
                              hipStream_t stream) {
    const float* x      = (const float*)d_in[0];   // [N,1]
    const int*   ei     = (const int*)  d_in[1];   // [2,E] row-major: row then col
    const float* conv_w = (const float*)d_in[2];   // [1,1]
    const float* conv_b = (const float*)d_in[3];   // [1]
    const float* fc_w   = (const float*)d_in[4];   // [2,50]
    const float* fc_b   = (const float*)d_in[5];   // [2]
    float* out = (float*)d_out;                    // [G,2]

    const int* row = ei;
    const int* col = ei + EDGES;

    // Workspace layout: [deg: N floats][t: N floats][s: N floats]
    float* deg = (float*)d_ws;
    float* t   = deg + NODES;
    float* s   = t + NODES;

    // Zero the two accumulator arrays (deg, t are contiguous).
    hipMemsetAsync(d_ws, 0, 2ull * NODES * sizeof(float), stream);

    int eblocks = (EDGES / 4 + 255) / 256;
    int nblocks = (NODES / 4 + 255) / 256;
    int gblocks = (GRAPHS + 255) / 256;

    k_deg<<<eblocks, 256, 0, stream>>>((const int4*)col, deg);
    k_scale<<<nblocks, 256, 0, stream>>>((const float4*)x, (const float4*)deg,
                                         conv_w, (float4*)s);
    k_scatter<<<eblocks, 256, 0, stream>>>((const int4*)row, (const int4*)col, s, t);
    k_final<<<gblocks, 256, 0, stream>>>(x, deg, t, conv_w, conv_b, fc_w, fc_b, out);
}